// Round 5
// baseline (698.778 us; speedup 1.0000x reference)
//
#include <hip/hip_runtime.h>
#include <hip/hip_bf16.h>

// RGCN: N=50000, R=16, H=32, L=8, E=1600000. All float tensors f32.
// Build: counting sort by seg = dst*16 + rel (rank pass = 1.6M atomics,
// scan -> combo[seg] = (offs<<8)|cnt, atomic-free place; csr = ushort src).
// Layers: uniform 16-relation run loops. Per edge: 1 csr ushort + one
// float4 (lane owns h-chunk; 8 lanes tile the 128B row) + 4 adds. Per run:
// norm applied once; layer2 does the W2 MAC per-run from conflict-free
// padded LDS (stride 36), root2 as virtual run, butterfly-shfl reduce.
#define Nn 50000
#define Rr 16
#define Hh 32
#define Ll 8
#define Ee 1600000
#define NSEG 800000

// ---- pass 1: count + rank in one atomic ----
__global__ __launch_bounds__(256) void rank_kernel(
        const int* __restrict__ etype, const int* __restrict__ dst,
        int* __restrict__ cnt, unsigned* __restrict__ pack) {
    int e = blockIdx.x * blockDim.x + threadIdx.x;
    if (e >= Ee) return;
    unsigned seg = (unsigned)((dst[e] << 4) | etype[e]);
    unsigned rank = (unsigned)atomicAdd(&cnt[seg], 1);
    pack[e] = (seg << 8) | rank;
}

// ---- exclusive scan over cnt[NSEG], 4 elems/thread ----
__global__ __launch_bounds__(256) void scan1_kernel(
        const int4* __restrict__ cnt4, int4* __restrict__ offs4,
        int* __restrict__ bsum) {
    __shared__ int sm[256];
    int i4 = blockIdx.x * 256 + threadIdx.x;
    int4 v = make_int4(0, 0, 0, 0);
    if (i4 < NSEG / 4) v = cnt4[i4];
    int s0 = v.x, s1 = s0 + v.y, s2 = s1 + v.z, s3 = s2 + v.w;
    sm[threadIdx.x] = s3;
    __syncthreads();
    for (int off = 1; off < 256; off <<= 1) {
        int add = (threadIdx.x >= off) ? sm[threadIdx.x - off] : 0;
        __syncthreads();
        sm[threadIdx.x] += add;
        __syncthreads();
    }
    int base = sm[threadIdx.x] - s3;
    if (i4 < NSEG / 4)
        offs4[i4] = make_int4(base, base + s0, base + s1, base + s2);
    if (threadIdx.x == 255) bsum[blockIdx.x] = sm[255];
}

__global__ __launch_bounds__(1024) void scan2_kernel(
        const int* __restrict__ bsum, int* __restrict__ boff, int nblk) {
    __shared__ int sm[1024];
    int v = (threadIdx.x < nblk) ? bsum[threadIdx.x] : 0;
    sm[threadIdx.x] = v;
    __syncthreads();
    for (int off = 1; off < 1024; off <<= 1) {
        int add = (threadIdx.x >= off) ? sm[threadIdx.x - off] : 0;
        __syncthreads();
        sm[threadIdx.x] += add;
        __syncthreads();
    }
    if (threadIdx.x < nblk) boff[threadIdx.x] = sm[threadIdx.x] - v;
}

// finalize: combo[seg] = ((offs+boff)<<8) | cnt
__global__ __launch_bounds__(256) void scan3_kernel(
        int4* __restrict__ offs4, const int* __restrict__ boff,
        const int4* __restrict__ cnt4) {
    int i4 = blockIdx.x * 256 + threadIdx.x;
    if (i4 < NSEG / 4) {
        int b = boff[blockIdx.x];
        int4 v = offs4[i4];
        int4 c = cnt4[i4];
        int4 o;
        o.x = ((v.x + b) << 8) | c.x;
        o.y = ((v.y + b) << 8) | c.y;
        o.z = ((v.z + b) << 8) | c.z;
        o.w = ((v.w + b) << 8) | c.w;
        offs4[i4] = o;   // combo, in place
    }
}

// ---- pass 2: atomic-free placement, ushort payload ----
__global__ __launch_bounds__(256) void place_kernel(
        const int* __restrict__ src, const unsigned* __restrict__ pack,
        const unsigned* __restrict__ combo, unsigned short* __restrict__ csr16) {
    int e = blockIdx.x * blockDim.x + threadIdx.x;
    if (e >= Ee) return;
    unsigned p = pack[e];
    unsigned seg = p >> 8, rank = p & 255u;
    unsigned pos = (combo[seg] >> 8) + rank;
    csr16[pos] = (unsigned short)src[e];
}

// ---- layer 1: h1[d] = relu(sum_r norm_r * sum_{e in run r} W1[r,s_e,:]
//                            + root1[d] + b1) ----
// 8 lanes/dst, lane owns 4 channels. Uniform 16-run loop, norm at boundary.
__global__ __launch_bounds__(256) void layer1_kernel(
        const unsigned short* __restrict__ csr16, const int* __restrict__ combo,
        const float* __restrict__ W1, const float* __restrict__ root1,
        const float* __restrict__ b1, float* __restrict__ h1) {
    __shared__ float rcp_tab[256];
    rcp_tab[threadIdx.x] = 1.0f / (float)(threadIdx.x ? threadIdx.x : 1);
    __syncthreads();
    int t = blockIdx.x * blockDim.x + threadIdx.x;
    int d = t >> 3, c = t & 7;
    if (d >= Nn) return;
    int e = ((const unsigned*)combo)[d << 4] >> 8;
    float4 acc = make_float4(0.f, 0.f, 0.f, 0.f);
    const float* Wc = W1 + (c << 2);
    const int4* combo4 = (const int4*)combo;
#pragma unroll
    for (int q = 0; q < 4; ++q) {
        int4 cc = combo4[(d << 2) + q];
        int lens[4] = {cc.x & 255, cc.y & 255, cc.z & 255, cc.w & 255};
#pragma unroll
        for (int j = 0; j < 4; ++j) {
            int len = lens[j];
            int r = (q << 2) | j;
            const float* Wr = Wc + (size_t)r * (Nn * Hh);
            float4 asum = make_float4(0.f, 0.f, 0.f, 0.f);
            for (int i = 0; i < len; ++i) {
                int s = csr16[e + i];
                float4 w = *(const float4*)(Wr + s * Hh);
                asum.x += w.x; asum.y += w.y; asum.z += w.z; asum.w += w.w;
            }
            e += len;
            float norm = rcp_tab[len];
            acc.x = fmaf(norm, asum.x, acc.x);
            acc.y = fmaf(norm, asum.y, acc.y);
            acc.z = fmaf(norm, asum.z, acc.z);
            acc.w = fmaf(norm, asum.w, acc.w);
        }
    }
    int hb = c << 2;
    const float4 rt = *(const float4*)(root1 + d * Hh + hb);
    const float4 bb = *(const float4*)(b1 + hb);
    float4 o;
    o.x = fmaxf(acc.x + rt.x + bb.x, 0.f);
    o.y = fmaxf(acc.y + rt.y + bb.y, 0.f);
    o.z = fmaxf(acc.z + rt.z + bb.z, 0.f);
    o.w = fmaxf(acc.w + rt.w + bb.w, 0.f);
    *(float4*)(h1 + d * Hh + hb) = o;
}

// ---- layer 2: out[d,l] = sigmoid(sum_r norm_r*(sum_e h1[s_e])·W2[r,:,l]
//                                  + h1[d]·root2[:,l] + b2[l]) ----
// 8 lanes/dst, lane owns h-chunk c (4 floats). Per edge: 1 csr + 1 float4 +
// 4 adds. Per run: 8 conflict-free ds_read_b128 + 32 fma. root2 = virtual
// run with norm=1, s=d. Butterfly shfl_xor reduce, coalesced store.
#define W2C 36   // padded chunk stride (32 floats + 4): lanes tile all banks
__global__ __launch_bounds__(256) void layer2_kernel(
        const unsigned short* __restrict__ csr16, const int* __restrict__ combo,
        const float* __restrict__ h1, const float* __restrict__ W2,
        const float* __restrict__ root2, const float* __restrict__ b2,
        float* __restrict__ out) {
    __shared__ float W2s[Rr * 8 * W2C];   // [r][c][k], k=j*8+l
    __shared__ float r2s[8 * W2C];
    __shared__ float b2s[Ll];
    __shared__ float rcp_tab[256];
    rcp_tab[threadIdx.x] = 1.0f / (float)(threadIdx.x ? threadIdx.x : 1);
    for (int idx = threadIdx.x; idx < Rr * Hh * Ll; idx += 256) {
        int r = idx >> 8, rem = idx & 255;
        W2s[r * (8 * W2C) + (rem >> 5) * W2C + (rem & 31)] = W2[idx];
    }
    for (int idx = threadIdx.x; idx < Hh * Ll; idx += 256)
        r2s[(idx >> 5) * W2C + (idx & 31)] = root2[idx];
    if (threadIdx.x < Ll) b2s[threadIdx.x] = b2[threadIdx.x];
    __syncthreads();

    int t = blockIdx.x * blockDim.x + threadIdx.x;
    int d = t >> 3, c = t & 7;
    if (d >= Nn) return;
    int e = ((const unsigned*)combo)[d << 4] >> 8;
    float acc[8] = {0.f, 0.f, 0.f, 0.f, 0.f, 0.f, 0.f, 0.f};
    const int4* combo4 = (const int4*)combo;
    const int hb = c << 2;
#pragma unroll
    for (int q = 0; q < 4; ++q) {
        int4 cc = combo4[(d << 2) + q];
        int lens[4] = {cc.x & 255, cc.y & 255, cc.z & 255, cc.w & 255};
#pragma unroll
        for (int j = 0; j < 4; ++j) {
            int len = lens[j];
            int r = (q << 2) | j;
            float4 asum = make_float4(0.f, 0.f, 0.f, 0.f);
            for (int i = 0; i < len; ++i) {
                int s = csr16[e + i];
                float4 hv = *(const float4*)(h1 + s * Hh + hb);
                asum.x += hv.x; asum.y += hv.y; asum.z += hv.z; asum.w += hv.w;
            }
            e += len;
            float norm = rcp_tab[len];
            float4 sa;
            sa.x = norm * asum.x; sa.y = norm * asum.y;
            sa.z = norm * asum.z; sa.w = norm * asum.w;
            const float* w = &W2s[r * (8 * W2C) + c * W2C];
#pragma unroll
            for (int j2 = 0; j2 < 4; ++j2) {
                float saj = (j2 == 0) ? sa.x : (j2 == 1) ? sa.y : (j2 == 2) ? sa.z : sa.w;
                float4 w0 = *(const float4*)(w + j2 * 8);
                float4 w1 = *(const float4*)(w + j2 * 8 + 4);
                acc[0] = fmaf(saj, w0.x, acc[0]);
                acc[1] = fmaf(saj, w0.y, acc[1]);
                acc[2] = fmaf(saj, w0.z, acc[2]);
                acc[3] = fmaf(saj, w0.w, acc[3]);
                acc[4] = fmaf(saj, w1.x, acc[4]);
                acc[5] = fmaf(saj, w1.y, acc[5]);
                acc[6] = fmaf(saj, w1.z, acc[6]);
                acc[7] = fmaf(saj, w1.w, acc[7]);
            }
        }
    }
    // virtual run: root2 with norm=1, s=d
    {
        float4 hv = *(const float4*)(h1 + d * Hh + hb);
        const float* w = &r2s[c * W2C];
#pragma unroll
        for (int j2 = 0; j2 < 4; ++j2) {
            float saj = (j2 == 0) ? hv.x : (j2 == 1) ? hv.y : (j2 == 2) ? hv.z : hv.w;
            float4 w0 = *(const float4*)(w + j2 * 8);
            float4 w1 = *(const float4*)(w + j2 * 8 + 4);
            acc[0] = fmaf(saj, w0.x, acc[0]);
            acc[1] = fmaf(saj, w0.y, acc[1]);
            acc[2] = fmaf(saj, w0.z, acc[2]);
            acc[3] = fmaf(saj, w0.w, acc[3]);
            acc[4] = fmaf(saj, w1.x, acc[4]);
            acc[5] = fmaf(saj, w1.y, acc[5]);
            acc[6] = fmaf(saj, w1.z, acc[6]);
            acc[7] = fmaf(saj, w1.w, acc[7]);
        }
    }
    // butterfly reduce across the 8 lanes of the dst group
#pragma unroll
    for (int m = 1; m <= 4; m <<= 1) {
#pragma unroll
        for (int l = 0; l < 8; ++l)
            acc[l] += __shfl_xor(acc[l], m, 64);
    }
    // lane c emits output channel c
    float myv = acc[0];
#pragma unroll
    for (int l = 1; l < 8; ++l) myv = (c == l) ? acc[l] : myv;
    float o = myv + b2s[c];
    out[(d << 3) | c] = 1.0f / (1.0f + __expf(-o));
}

extern "C" void kernel_launch(void* const* d_in, const int* in_sizes, int n_in,
                              void* d_out, int out_size, void* d_ws, size_t ws_size,
                              hipStream_t stream) {
    const int* edge_index = (const int*)d_in[0];   // (2, E) int32
    const int* etype      = (const int*)d_in[1];   // (E,)  int32
    const float* W1    = (const float*)d_in[2];    // (R,N,H) f32
    const float* root1 = (const float*)d_in[3];    // (N,H)
    const float* b1    = (const float*)d_in[4];    // (H,)
    const float* W2    = (const float*)d_in[5];    // (R,H,L)
    const float* root2 = (const float*)d_in[6];    // (H,L)
    const float* b2    = (const float*)d_in[7];    // (L,)
    float* out = (float*)d_out;                    // (N, L) f32

    const int* src = edge_index;       // row 0
    const int* dst = edge_index + Ee;  // row 1

    // workspace (int32 units), overlays by liveness:
    //   combo  [0,       800016)   scan1 partial -> scan3 combo -> layers
    //   csr16  [800016,  1600016)  1.6M ushort, written by place
    //   cnt    [1600016, 2400016)  rank->scan3, then dead
    //   pack   [2400016, 4000016)  rank -> place
    //   h1     [2400016, 4000016)  SAME region; layer1 writes (pack dead)
    //   bsum   [4000016, 4000800), boff [4000800, 4001616)
    int* ws = (int*)d_ws;
    int* combo          = ws;
    unsigned short* csr16 = (unsigned short*)(ws + 800016);
    int* cnt            = ws + 1600016;
    unsigned* pack      = (unsigned*)(ws + 2400016);
    float* h1           = (float*)(ws + 2400016);
    int* bsum           = ws + 4000016;
    int* boff           = ws + 4000800;

    if (ws_size < (size_t)4001616 * sizeof(int)) return;  // diagnostic guard

    hipMemsetAsync(cnt, 0, (size_t)NSEG * sizeof(int), stream);

    const int nblkE = (Ee + 255) / 256;           // 6250
    const int nblkS = (NSEG / 4 + 255) / 256;     // 782

    rank_kernel<<<nblkE, 256, 0, stream>>>(etype, dst, cnt, pack);
    scan1_kernel<<<nblkS, 256, 0, stream>>>((const int4*)cnt, (int4*)combo, bsum);
    scan2_kernel<<<1, 1024, 0, stream>>>(bsum, boff, nblkS);
    scan3_kernel<<<nblkS, 256, 0, stream>>>((int4*)combo, boff, (const int4*)cnt);
    place_kernel<<<nblkE, 256, 0, stream>>>(src, pack, (const unsigned*)combo, csr16);
    layer1_kernel<<<(Nn * 8 + 255) / 256, 256, 0, stream>>>(csr16, combo, W1, root1, b1, h1);
    layer2_kernel<<<(Nn * 8 + 255) / 256, 256, 0, stream>>>(csr16, combo, h1, W2, root2, b2, out);
}

// Round 6
// 404.330 us; speedup vs baseline: 1.7282x; 1.7282x over previous
//
#include <hip/hip_runtime.h>
#include <hip/hip_bf16.h>

// RGCN: N=50000, R=16, H=32, L=8, E=1600000. All float tensors f32.
// Build: counting sort by seg = dst*16 + rel (rank pass = 1.6M atomics,
// scan -> combo[seg] = (offs<<8)|cnt, atomic-free place; csr = ushort src).
// Layers: run-sum structure -- per relation run accumulate UNWEIGHTED sums,
// apply norm (and in layer2 the W2 MAC) once per run. Round-6 fix vs round 5:
// the 16-relation loop is a DYNAMIC `#pragma unroll 1` loop (round 5's full
// unroll spilled: VGPR=256, WRITE_SIZE 106MB of scratch, occupancy 9.7%).
#define Nn 50000
#define Rr 16
#define Hh 32
#define Ll 8
#define Ee 1600000
#define NSEG 800000
#define W2C 36   // padded (r,c)-chunk pitch: 8 c-chunks tile all 32 banks

// ---- pass 1: count + rank in one atomic ----
__global__ __launch_bounds__(256) void rank_kernel(
        const int* __restrict__ etype, const int* __restrict__ dst,
        int* __restrict__ cnt, unsigned* __restrict__ pack) {
    int e = blockIdx.x * blockDim.x + threadIdx.x;
    if (e >= Ee) return;
    unsigned seg = (unsigned)((dst[e] << 4) | etype[e]);
    unsigned rank = (unsigned)atomicAdd(&cnt[seg], 1);
    pack[e] = (seg << 8) | rank;
}

// ---- exclusive scan over cnt[NSEG], 4 elems/thread ----
__global__ __launch_bounds__(256) void scan1_kernel(
        const int4* __restrict__ cnt4, int4* __restrict__ offs4,
        int* __restrict__ bsum) {
    __shared__ int sm[256];
    int i4 = blockIdx.x * 256 + threadIdx.x;
    int4 v = make_int4(0, 0, 0, 0);
    if (i4 < NSEG / 4) v = cnt4[i4];
    int s0 = v.x, s1 = s0 + v.y, s2 = s1 + v.z, s3 = s2 + v.w;
    sm[threadIdx.x] = s3;
    __syncthreads();
    for (int off = 1; off < 256; off <<= 1) {
        int add = (threadIdx.x >= off) ? sm[threadIdx.x - off] : 0;
        __syncthreads();
        sm[threadIdx.x] += add;
        __syncthreads();
    }
    int base = sm[threadIdx.x] - s3;
    if (i4 < NSEG / 4)
        offs4[i4] = make_int4(base, base + s0, base + s1, base + s2);
    if (threadIdx.x == 255) bsum[blockIdx.x] = sm[255];
}

__global__ __launch_bounds__(1024) void scan2_kernel(
        const int* __restrict__ bsum, int* __restrict__ boff, int nblk) {
    __shared__ int sm[1024];
    int v = (threadIdx.x < nblk) ? bsum[threadIdx.x] : 0;
    sm[threadIdx.x] = v;
    __syncthreads();
    for (int off = 1; off < 1024; off <<= 1) {
        int add = (threadIdx.x >= off) ? sm[threadIdx.x - off] : 0;
        __syncthreads();
        sm[threadIdx.x] += add;
        __syncthreads();
    }
    if (threadIdx.x < nblk) boff[threadIdx.x] = sm[threadIdx.x] - v;
}

// finalize: combo[seg] = ((offs+boff)<<8) | cnt
__global__ __launch_bounds__(256) void scan3_kernel(
        int4* __restrict__ offs4, const int* __restrict__ boff,
        const int4* __restrict__ cnt4) {
    int i4 = blockIdx.x * 256 + threadIdx.x;
    if (i4 < NSEG / 4) {
        int b = boff[blockIdx.x];
        int4 v = offs4[i4];
        int4 c = cnt4[i4];
        int4 o;
        o.x = ((v.x + b) << 8) | c.x;
        o.y = ((v.y + b) << 8) | c.y;
        o.z = ((v.z + b) << 8) | c.z;
        o.w = ((v.w + b) << 8) | c.w;
        offs4[i4] = o;   // combo, in place
    }
}

// ---- pass 2: atomic-free placement, ushort payload ----
__global__ __launch_bounds__(256) void place_kernel(
        const int* __restrict__ src, const unsigned* __restrict__ pack,
        const unsigned* __restrict__ combo, unsigned short* __restrict__ csr16) {
    int e = blockIdx.x * blockDim.x + threadIdx.x;
    if (e >= Ee) return;
    unsigned p = pack[e];
    unsigned seg = p >> 8, rank = p & 255u;
    unsigned pos = (combo[seg] >> 8) + rank;
    csr16[pos] = (unsigned short)src[e];
}

// ---- layer 1: h1[d] = relu(sum_r norm_r * sum_{e in run r} W1[r,s_e,:]
//                            + root1[d] + b1) ----
// 8 lanes/dst, lane owns 4 channels. Dynamic (non-unrolled) 16-run loop.
__global__ __launch_bounds__(256) void layer1_kernel(
        const unsigned short* __restrict__ csr16, const unsigned* __restrict__ combo,
        const float* __restrict__ W1, const float* __restrict__ root1,
        const float* __restrict__ b1, float* __restrict__ h1) {
    __shared__ float rcp_tab[256];
    rcp_tab[threadIdx.x] = 1.0f / (float)(threadIdx.x ? threadIdx.x : 1);
    __syncthreads();
    int t = blockIdx.x * blockDim.x + threadIdx.x;
    int d = t >> 3, c = t & 7;
    if (d >= Nn) return;
    int e = (int)(combo[d << 4] >> 8);
    float4 acc = make_float4(0.f, 0.f, 0.f, 0.f);
    const float* Wc = W1 + (c << 2);
#pragma unroll 1
    for (int r = 0; r < Rr; ++r) {
        int len = (int)(combo[(d << 4) + r] & 255u);
        const float* Wr = Wc + (size_t)r * (Nn * Hh);
        float4 asum = make_float4(0.f, 0.f, 0.f, 0.f);
        for (int i = 0; i < len; ++i) {
            int s = csr16[e + i];
            float4 w = *(const float4*)(Wr + s * Hh);
            asum.x += w.x; asum.y += w.y; asum.z += w.z; asum.w += w.w;
        }
        e += len;
        float norm = rcp_tab[len];
        acc.x = fmaf(norm, asum.x, acc.x);
        acc.y = fmaf(norm, asum.y, acc.y);
        acc.z = fmaf(norm, asum.z, acc.z);
        acc.w = fmaf(norm, asum.w, acc.w);
    }
    int hb = c << 2;
    const float4 rt = *(const float4*)(root1 + d * Hh + hb);
    const float4 bb = *(const float4*)(b1 + hb);
    float4 o;
    o.x = fmaxf(acc.x + rt.x + bb.x, 0.f);
    o.y = fmaxf(acc.y + rt.y + bb.y, 0.f);
    o.z = fmaxf(acc.z + rt.z + bb.z, 0.f);
    o.w = fmaxf(acc.w + rt.w + bb.w, 0.f);
    *(float4*)(h1 + d * Hh + hb) = o;
}

// ---- layer 2: out[d,l] = sigmoid(sum_r norm_r*(sum_e h1[s_e])·W2[r,:,l]
//                                  + h1[d]·root2[:,l] + b2[l]) ----
// 8 lanes/dst, lane owns h-chunk c (4 floats). Per edge: 1 csr + 1 float4 +
// 4 adds. Per run: 8 conflict-free ds_read_b128 + 32 fma (dynamic r loop).
// root2 = virtual run with norm=1, s=d. Butterfly shfl_xor reduce.
__global__ __launch_bounds__(256) void layer2_kernel(
        const unsigned short* __restrict__ csr16, const unsigned* __restrict__ combo,
        const float* __restrict__ h1, const float* __restrict__ W2,
        const float* __restrict__ root2, const float* __restrict__ b2,
        float* __restrict__ out) {
    __shared__ float W2s[Rr * 8 * W2C];   // [r][c][k], k=j2*8+l
    __shared__ float r2s[8 * W2C];
    __shared__ float b2s[Ll];
    __shared__ float rcp_tab[256];
    rcp_tab[threadIdx.x] = 1.0f / (float)(threadIdx.x ? threadIdx.x : 1);
    for (int idx = threadIdx.x; idx < Rr * Hh * Ll; idx += 256) {
        int r = idx >> 8, rem = idx & 255;
        W2s[r * (8 * W2C) + (rem >> 5) * W2C + (rem & 31)] = W2[idx];
    }
    for (int idx = threadIdx.x; idx < Hh * Ll; idx += 256)
        r2s[(idx >> 5) * W2C + (idx & 31)] = root2[idx];
    if (threadIdx.x < Ll) b2s[threadIdx.x] = b2[threadIdx.x];
    __syncthreads();

    int t = blockIdx.x * blockDim.x + threadIdx.x;
    int d = t >> 3, c = t & 7;
    if (d >= Nn) return;
    int e = (int)(combo[d << 4] >> 8);
    float acc[8] = {0.f, 0.f, 0.f, 0.f, 0.f, 0.f, 0.f, 0.f};
    const int hb = c << 2;
#pragma unroll 1
    for (int r = 0; r < Rr; ++r) {
        int len = (int)(combo[(d << 4) + r] & 255u);
        float4 asum = make_float4(0.f, 0.f, 0.f, 0.f);
        for (int i = 0; i < len; ++i) {
            int s = csr16[e + i];
            float4 hv = *(const float4*)(h1 + s * Hh + hb);
            asum.x += hv.x; asum.y += hv.y; asum.z += hv.z; asum.w += hv.w;
        }
        e += len;
        float norm = rcp_tab[len];
        float4 sa;
        sa.x = norm * asum.x; sa.y = norm * asum.y;
        sa.z = norm * asum.z; sa.w = norm * asum.w;
        const float* w = &W2s[(r * 8 + c) * W2C];
#pragma unroll
        for (int j2 = 0; j2 < 4; ++j2) {
            float saj = (j2 == 0) ? sa.x : (j2 == 1) ? sa.y : (j2 == 2) ? sa.z : sa.w;
            float4 w0 = *(const float4*)(w + j2 * 8);
            float4 w1 = *(const float4*)(w + j2 * 8 + 4);
            acc[0] = fmaf(saj, w0.x, acc[0]);
            acc[1] = fmaf(saj, w0.y, acc[1]);
            acc[2] = fmaf(saj, w0.z, acc[2]);
            acc[3] = fmaf(saj, w0.w, acc[3]);
            acc[4] = fmaf(saj, w1.x, acc[4]);
            acc[5] = fmaf(saj, w1.y, acc[5]);
            acc[6] = fmaf(saj, w1.z, acc[6]);
            acc[7] = fmaf(saj, w1.w, acc[7]);
        }
    }
    // virtual run: root2 with norm=1, s=d
    {
        float4 hv = *(const float4*)(h1 + d * Hh + hb);
        const float* w = &r2s[c * W2C];
#pragma unroll
        for (int j2 = 0; j2 < 4; ++j2) {
            float saj = (j2 == 0) ? hv.x : (j2 == 1) ? hv.y : (j2 == 2) ? hv.z : hv.w;
            float4 w0 = *(const float4*)(w + j2 * 8);
            float4 w1 = *(const float4*)(w + j2 * 8 + 4);
            acc[0] = fmaf(saj, w0.x, acc[0]);
            acc[1] = fmaf(saj, w0.y, acc[1]);
            acc[2] = fmaf(saj, w0.z, acc[2]);
            acc[3] = fmaf(saj, w0.w, acc[3]);
            acc[4] = fmaf(saj, w1.x, acc[4]);
            acc[5] = fmaf(saj, w1.y, acc[5]);
            acc[6] = fmaf(saj, w1.z, acc[6]);
            acc[7] = fmaf(saj, w1.w, acc[7]);
        }
    }
    // butterfly reduce across the 8 lanes of the dst group
#pragma unroll
    for (int m = 1; m <= 4; m <<= 1) {
#pragma unroll
        for (int l = 0; l < 8; ++l)
            acc[l] += __shfl_xor(acc[l], m, 64);
    }
    // lane c emits output channel c
    float myv = acc[0];
#pragma unroll
    for (int l = 1; l < 8; ++l) myv = (c == l) ? acc[l] : myv;
    float o = myv + b2s[c];
    out[(d << 3) | c] = 1.0f / (1.0f + __expf(-o));
}

extern "C" void kernel_launch(void* const* d_in, const int* in_sizes, int n_in,
                              void* d_out, int out_size, void* d_ws, size_t ws_size,
                              hipStream_t stream) {
    const int* edge_index = (const int*)d_in[0];   // (2, E) int32
    const int* etype      = (const int*)d_in[1];   // (E,)  int32
    const float* W1    = (const float*)d_in[2];    // (R,N,H) f32
    const float* root1 = (const float*)d_in[3];    // (N,H)
    const float* b1    = (const float*)d_in[4];    // (H,)
    const float* W2    = (const float*)d_in[5];    // (R,H,L)
    const float* root2 = (const float*)d_in[6];    // (H,L)
    const float* b2    = (const float*)d_in[7];    // (L,)
    float* out = (float*)d_out;                    // (N, L) f32

    const int* src = edge_index;       // row 0
    const int* dst = edge_index + Ee;  // row 1

    // workspace (int32 units), overlays by liveness:
    //   combo  [0,       800016)   scan1 partial -> scan3 combo -> layers
    //   csr16  [800016,  1600016)  1.6M ushort, written by place
    //   cnt    [1600016, 2400016)  rank->scan3, then dead
    //   pack   [2400016, 4000016)  rank -> place
    //   h1     [2400016, 4000016)  SAME region; layer1 writes (pack dead)
    //   bsum   [4000016, 4000800), boff [4000800, 4001616)
    int* ws = (int*)d_ws;
    int* combo            = ws;
    unsigned short* csr16 = (unsigned short*)(ws + 800016);
    int* cnt              = ws + 1600016;
    unsigned* pack        = (unsigned*)(ws + 2400016);
    float* h1             = (float*)(ws + 2400016);
    int* bsum             = ws + 4000016;
    int* boff             = ws + 4000800;

    if (ws_size < (size_t)4001616 * sizeof(int)) return;  // diagnostic guard

    hipMemsetAsync(cnt, 0, (size_t)NSEG * sizeof(int), stream);

    const int nblkE = (Ee + 255) / 256;           // 6250
    const int nblkS = (NSEG / 4 + 255) / 256;     // 782

    rank_kernel<<<nblkE, 256, 0, stream>>>(etype, dst, cnt, pack);
    scan1_kernel<<<nblkS, 256, 0, stream>>>((const int4*)cnt, (int4*)combo, bsum);
    scan2_kernel<<<1, 1024, 0, stream>>>(bsum, boff, nblkS);
    scan3_kernel<<<nblkS, 256, 0, stream>>>((int4*)combo, boff, (const int4*)cnt);
    place_kernel<<<nblkE, 256, 0, stream>>>(src, pack, (const unsigned*)combo, csr16);
    layer1_kernel<<<(Nn * 8 + 255) / 256, 256, 0, stream>>>(csr16, (const unsigned*)combo, W1, root1, b1, h1);
    layer2_kernel<<<(Nn * 8 + 255) / 256, 256, 0, stream>>>(csr16, (const unsigned*)combo, h1, W2, root2, b2, out);
}

// Round 7
// 378.397 us; speedup vs baseline: 1.8467x; 1.0685x over previous
//
#include <hip/hip_runtime.h>
#include <hip/hip_bf16.h>

// RGCN: N=50000, R=16, H=32, L=8, E=1600000. All float tensors f32.
// Build: counting sort by seg = dst*16 + rel. rank (1.6M atomics) ->
// scan (combo[seg]=(offs<<8)|cnt, sentinel combo[NSEG]) -> place
// (atomic-free, csr32[pos]=(r<<24)|(k<<16)|src).
// Layers (round 7): ONE WAVE PER DST, lanes = 8 edge-slots x 8 h-chunks.
// Each batch issues 8 independent 128B gathers per wave-instr (8x MLP vs
// round 6's serial per-group walk that ran at 14% HBM). Tail handled
// branchlessly (s/r/norm selected before address calc). Layer2 MACs W2 per
// edge from conflict-free padded LDS (W2C=36, 0 conflicts measured r6),
// root2 = virtual relation 16, 6-step butterfly reduce.
#define Nn 50000
#define Rr 16
#define Hh 32
#define Ll 8
#define Ee 1600000
#define NSEG 800000
#define W2C 36

// ---- pass 1: count + rank in one atomic ----
__global__ __launch_bounds__(256) void rank_kernel(
        const int* __restrict__ etype, const int* __restrict__ dst,
        int* __restrict__ cnt, unsigned* __restrict__ pack) {
    int e = blockIdx.x * blockDim.x + threadIdx.x;
    if (e >= Ee) return;
    unsigned seg = (unsigned)((dst[e] << 4) | etype[e]);
    unsigned rank = (unsigned)atomicAdd(&cnt[seg], 1);
    pack[e] = (seg << 8) | rank;
}

// ---- exclusive scan over cnt[NSEG], 4 elems/thread ----
__global__ __launch_bounds__(256) void scan1_kernel(
        const int4* __restrict__ cnt4, int4* __restrict__ offs4,
        int* __restrict__ bsum) {
    __shared__ int sm[256];
    int i4 = blockIdx.x * 256 + threadIdx.x;
    int4 v = make_int4(0, 0, 0, 0);
    if (i4 < NSEG / 4) v = cnt4[i4];
    int s0 = v.x, s1 = s0 + v.y, s2 = s1 + v.z, s3 = s2 + v.w;
    sm[threadIdx.x] = s3;
    __syncthreads();
    for (int off = 1; off < 256; off <<= 1) {
        int add = (threadIdx.x >= off) ? sm[threadIdx.x - off] : 0;
        __syncthreads();
        sm[threadIdx.x] += add;
        __syncthreads();
    }
    int base = sm[threadIdx.x] - s3;
    if (i4 < NSEG / 4)
        offs4[i4] = make_int4(base, base + s0, base + s1, base + s2);
    if (threadIdx.x == 255) bsum[blockIdx.x] = sm[255];
}

__global__ __launch_bounds__(1024) void scan2_kernel(
        const int* __restrict__ bsum, int* __restrict__ boff, int nblk) {
    __shared__ int sm[1024];
    int v = (threadIdx.x < nblk) ? bsum[threadIdx.x] : 0;
    sm[threadIdx.x] = v;
    __syncthreads();
    for (int off = 1; off < 1024; off <<= 1) {
        int add = (threadIdx.x >= off) ? sm[threadIdx.x - off] : 0;
        __syncthreads();
        sm[threadIdx.x] += add;
        __syncthreads();
    }
    if (threadIdx.x < nblk) boff[threadIdx.x] = sm[threadIdx.x] - v;
}

// finalize: combo[seg] = ((offs+boff)<<8) | cnt ; sentinel combo[NSEG]=Ee<<8
__global__ __launch_bounds__(256) void scan3_kernel(
        int4* __restrict__ offs4, const int* __restrict__ boff,
        const int4* __restrict__ cnt4, int* __restrict__ combo) {
    int i4 = blockIdx.x * 256 + threadIdx.x;
    if (i4 < NSEG / 4) {
        int b = boff[blockIdx.x];
        int4 v = offs4[i4];
        int4 c = cnt4[i4];
        int4 o;
        o.x = ((v.x + b) << 8) | c.x;
        o.y = ((v.y + b) << 8) | c.y;
        o.z = ((v.z + b) << 8) | c.z;
        o.w = ((v.w + b) << 8) | c.w;
        offs4[i4] = o;   // combo, in place
    }
    if (i4 == 0) combo[NSEG] = (Ee << 8);
}

// ---- pass 2: atomic-free placement, (r,k,src) payload ----
__global__ __launch_bounds__(256) void place_kernel(
        const int* __restrict__ src, const unsigned* __restrict__ pack,
        const unsigned* __restrict__ combo, unsigned* __restrict__ csr32) {
    int e = blockIdx.x * blockDim.x + threadIdx.x;
    if (e >= Ee) return;
    unsigned p = pack[e];
    unsigned seg = p >> 8, rank = p & 255u;
    unsigned c = combo[seg];
    unsigned pos = (c >> 8) + rank;
    unsigned k = c & 255u;
    unsigned r = seg & 15u;
    csr32[pos] = (r << 24) | (k << 16) | (unsigned)src[e];
}

// ---- layer 1: wave per dst; lane = slot(8) x chunk(8) ----
__global__ __launch_bounds__(256) void layer1_kernel(
        const unsigned* __restrict__ csr32, const unsigned* __restrict__ combo,
        const float* __restrict__ W1, const float* __restrict__ root1,
        const float* __restrict__ b1, float* __restrict__ h1) {
    int d = (blockIdx.x * 256 + threadIdx.x) >> 6;
    int lane = threadIdx.x & 63;
    int slot = lane >> 3, chunk = lane & 7;
    if (d >= Nn) return;
    int beg = (int)(combo[d << 4] >> 8);
    int end = (int)(combo[(d + 1) << 4] >> 8);
    int deg = end - beg;
    float4 acc = make_float4(0.f, 0.f, 0.f, 0.f);
    const float* Wc = W1 + (chunk << 2);
    for (int i = 0; i < deg; i += 8) {
        int pos = i + slot;
        bool real = pos < deg;
        unsigned v = csr32[beg + (real ? pos : 0)];
        int s = real ? (int)(v & 0xffffu) : 0;
        int r = real ? (int)(v >> 24) : 0;
        float norm = real ? __builtin_amdgcn_rcpf((float)((v >> 16) & 255u)) : 0.f;
        float4 w = *(const float4*)(Wc + ((size_t)(r * Nn + s) << 5));
        acc.x = fmaf(norm, w.x, acc.x);
        acc.y = fmaf(norm, w.y, acc.y);
        acc.z = fmaf(norm, w.z, acc.z);
        acc.w = fmaf(norm, w.w, acc.w);
    }
    // reduce over the 8 slots (xor lane bits 3,4,5)
#pragma unroll
    for (int m = 8; m <= 32; m <<= 1) {
        acc.x += __shfl_xor(acc.x, m, 64);
        acc.y += __shfl_xor(acc.y, m, 64);
        acc.z += __shfl_xor(acc.z, m, 64);
        acc.w += __shfl_xor(acc.w, m, 64);
    }
    if (slot == 0) {
        int hb = chunk << 2;
        float4 rt = *(const float4*)(root1 + (d << 5) + hb);
        float4 bb = *(const float4*)(b1 + hb);
        float4 o;
        o.x = fmaxf(acc.x + rt.x + bb.x, 0.f);
        o.y = fmaxf(acc.y + rt.y + bb.y, 0.f);
        o.z = fmaxf(acc.z + rt.z + bb.z, 0.f);
        o.w = fmaxf(acc.w + rt.w + bb.w, 0.f);
        *(float4*)(h1 + (d << 5) + hb) = o;   // lanes 0-7: one 128B line
    }
}

// ---- layer 2: wave per dst; per-edge W2 MAC from LDS; root2 = rel 16 ----
__global__ __launch_bounds__(256) void layer2_kernel(
        const unsigned* __restrict__ csr32, const unsigned* __restrict__ combo,
        const float* __restrict__ h1, const float* __restrict__ W2,
        const float* __restrict__ root2, const float* __restrict__ b2,
        float* __restrict__ out) {
    __shared__ float W2s[17 * 8 * W2C];   // [r][chunk][(h&3)*8 + l]
    for (int idx = threadIdx.x; idx < Rr * Hh * Ll; idx += 256) {
        int r = idx >> 8, h = (idx >> 3) & 31, l = idx & 7;
        W2s[((r << 3) | (h >> 2)) * W2C + ((h & 3) << 3) + l] = W2[idx];
    }
    for (int idx = threadIdx.x; idx < Hh * Ll; idx += 256) {
        int h = idx >> 3, l = idx & 7;
        W2s[(128 | (h >> 2)) * W2C + ((h & 3) << 3) + l] = root2[idx];
    }
    __syncthreads();

    int d = (blockIdx.x * 256 + threadIdx.x) >> 6;
    int lane = threadIdx.x & 63;
    int slot = lane >> 3, chunk = lane & 7;
    if (d >= Nn) return;
    int beg = (int)(combo[d << 4] >> 8);
    int end = (int)(combo[(d + 1) << 4] >> 8);
    int deg = end - beg;
    int degv = deg + 1;                 // + virtual root2 edge
    float acc[8] = {0.f, 0.f, 0.f, 0.f, 0.f, 0.f, 0.f, 0.f};
    const int hb = chunk << 2;
    for (int i = 0; i < degv; i += 8) {
        int pos = i + slot;
        bool real = pos < deg;
        bool virt = pos == deg;
        unsigned v = csr32[beg + (real ? pos : 0)];
        int s = virt ? d : (real ? (int)(v & 0xffffu) : 0);
        int r = virt ? 16 : (real ? (int)(v >> 24) : 0);
        float norm = virt ? 1.0f
                   : (real ? __builtin_amdgcn_rcpf((float)((v >> 16) & 255u)) : 0.f);
        float4 hv = *(const float4*)(h1 + (s << 5) + hb);
        float4 sa;
        sa.x = norm * hv.x; sa.y = norm * hv.y;
        sa.z = norm * hv.z; sa.w = norm * hv.w;
        const float* w = &W2s[((r << 3) | chunk) * W2C];
#pragma unroll
        for (int j2 = 0; j2 < 4; ++j2) {
            float saj = (j2 == 0) ? sa.x : (j2 == 1) ? sa.y : (j2 == 2) ? sa.z : sa.w;
            float4 w0 = *(const float4*)(w + j2 * 8);
            float4 w1 = *(const float4*)(w + j2 * 8 + 4);
            acc[0] = fmaf(saj, w0.x, acc[0]);
            acc[1] = fmaf(saj, w0.y, acc[1]);
            acc[2] = fmaf(saj, w0.z, acc[2]);
            acc[3] = fmaf(saj, w0.w, acc[3]);
            acc[4] = fmaf(saj, w1.x, acc[4]);
            acc[5] = fmaf(saj, w1.y, acc[5]);
            acc[6] = fmaf(saj, w1.z, acc[6]);
            acc[7] = fmaf(saj, w1.w, acc[7]);
        }
    }
    // butterfly over all 64 lanes (chunk bits 0-2, slot bits 3-5)
#pragma unroll
    for (int m = 1; m <= 32; m <<= 1) {
#pragma unroll
        for (int l = 0; l < 8; ++l)
            acc[l] += __shfl_xor(acc[l], m, 64);
    }
    if (lane < 8) {
        float myv = acc[0];
#pragma unroll
        for (int l = 1; l < 8; ++l) myv = (lane == l) ? acc[l] : myv;
        float o = myv + b2[lane];
        out[(d << 3) | lane] = 1.0f / (1.0f + __expf(-o));
    }
}

extern "C" void kernel_launch(void* const* d_in, const int* in_sizes, int n_in,
                              void* d_out, int out_size, void* d_ws, size_t ws_size,
                              hipStream_t stream) {
    const int* edge_index = (const int*)d_in[0];   // (2, E) int32
    const int* etype      = (const int*)d_in[1];   // (E,)  int32
    const float* W1    = (const float*)d_in[2];    // (R,N,H) f32
    const float* root1 = (const float*)d_in[3];    // (N,H)
    const float* b1    = (const float*)d_in[4];    // (H,)
    const float* W2    = (const float*)d_in[5];    // (R,H,L)
    const float* root2 = (const float*)d_in[6];    // (H,L)
    const float* b2    = (const float*)d_in[7];    // (L,)
    float* out = (float*)d_out;                    // (N, L) f32

    const int* src = edge_index;       // row 0
    const int* dst = edge_index + Ee;  // row 1

    // workspace (int32 units), overlays by liveness:
    //   combo  [0,       800016)   scan1 partial -> scan3 combo -> layers
    //   csr32  [800016,  2400016)  written by place (after cnt dies)
    //   cnt    [1600016, 2400016)  memset->rank->scan3, then dead
    //   pack   [2400016, 4000016)  rank -> place
    //   h1     [2400016, 4000016)  SAME region; layer1 writes (pack dead)
    //   bsum   [4000016, 4000800), boff [4000800, 4001616)
    int* ws = (int*)d_ws;
    int* combo      = ws;
    unsigned* csr32 = (unsigned*)(ws + 800016);
    int* cnt        = ws + 1600016;
    unsigned* pack  = (unsigned*)(ws + 2400016);
    float* h1       = (float*)(ws + 2400016);
    int* bsum       = ws + 4000016;
    int* boff       = ws + 4000800;

    if (ws_size < (size_t)4001616 * sizeof(int)) return;  // diagnostic guard

    hipMemsetAsync(cnt, 0, (size_t)NSEG * sizeof(int), stream);

    const int nblkE = (Ee + 255) / 256;           // 6250
    const int nblkS = (NSEG / 4 + 255) / 256;     // 782
    const int nblkL = (Nn * 64 + 255) / 256;      // 12500 (wave per dst)

    rank_kernel<<<nblkE, 256, 0, stream>>>(etype, dst, cnt, pack);
    scan1_kernel<<<nblkS, 256, 0, stream>>>((const int4*)cnt, (int4*)combo, bsum);
    scan2_kernel<<<1, 1024, 0, stream>>>(bsum, boff, nblkS);
    scan3_kernel<<<nblkS, 256, 0, stream>>>((int4*)combo, boff, (const int4*)cnt, combo);
    place_kernel<<<nblkE, 256, 0, stream>>>(src, pack, (const unsigned*)combo, csr32);
    layer1_kernel<<<nblkL, 256, 0, stream>>>(csr32, (const unsigned*)combo, W1, root1, b1, h1);
    layer2_kernel<<<nblkL, 256, 0, stream>>>(csr32, (const unsigned*)combo, h1, W2, root2, b2, out);
}

// Round 8
// 316.093 us; speedup vs baseline: 2.2107x; 1.1971x over previous
//
#include <hip/hip_runtime.h>
#include <hip/hip_bf16.h>

// RGCN: N=50000, R=16, H=32, L=8, E=1600000. Float tensors f32; h1 kept bf16.
// Build (round 8): ZERO global atomics. Two-level LDS bucket sort:
//   p1hist:  per-block (4096 edges) LDS histogram over 782 buckets (dst>>6),
//            written column-major histT[bucket][block].
//   scan:    3-kernel exclusive scan of histT in place -> offsT.
//   p1scat:  block re-ranks its edges in LDS (hist+scan+cursor), stages
//            payload (dl6<<20|r<<16|src), writes bucket-runs (~10 edges)
//            nearly-coalesced to pay[].
//   p2sort:  one block per bucket: LDS counting sort over 1024 (dl6,r) bins,
//            writes combo[seg]=(offs<<8)|cnt coalesced and csr32 in place.
// Layers: wave-per-dst 8-slot gather (round 7), h1 in bf16.
#define Nn 50000
#define Rr 16
#define Hh 32
#define Ll 8
#define Ee 1600000
#define NSEG 800000
#define NB 782          // buckets = dst>>6
#define CH 4096         // edges per partition block
#define NBLK1 391       // ceil(E/CH)
#define COLS 392        // histT row stride (NBLK1 padded; total NB*COLS div by 4)
#define HT_INT4 76636   // NB*COLS/4
#define CAP 3072        // max edges per bucket (mean 2048, +22 sigma)
#define W2C 36

__device__ __forceinline__ float bf2f(unsigned short u) {
    return __uint_as_float(((unsigned)u) << 16);
}
__device__ __forceinline__ unsigned short f2bf(float f) {
    unsigned u = __float_as_uint(f);
    return (unsigned short)((u + 0x7FFFu + ((u >> 16) & 1u)) >> 16);  // RNE
}

// ---- pass 1a: per-block bucket histogram (LDS atomics only) ----
__global__ __launch_bounds__(256) void p1hist_kernel(
        const int* __restrict__ dst, int* __restrict__ histT) {
    __shared__ int hist[1024];
    for (int i = threadIdx.x; i < 1024; i += 256) hist[i] = 0;
    __syncthreads();
    int base = blockIdx.x * CH;
    int n = min(CH, Ee - base);
    for (int i = threadIdx.x; i < n; i += 256)
        atomicAdd(&hist[dst[base + i] >> 6], 1);
    __syncthreads();
    for (int k = threadIdx.x; k < NB; k += 256)
        histT[k * COLS + blockIdx.x] = hist[k];
}

// ---- exclusive scan over histT (in place), 4 elems/thread ----
__global__ __launch_bounds__(256) void scan1_kernel(
        int4* data4, int* __restrict__ bsum) {
    __shared__ int sm[256];
    int i4 = blockIdx.x * 256 + threadIdx.x;
    int4 v = make_int4(0, 0, 0, 0);
    if (i4 < HT_INT4) v = data4[i4];
    int s0 = v.x, s1 = s0 + v.y, s2 = s1 + v.z, s3 = s2 + v.w;
    sm[threadIdx.x] = s3;
    __syncthreads();
    for (int off = 1; off < 256; off <<= 1) {
        int add = (threadIdx.x >= off) ? sm[threadIdx.x - off] : 0;
        __syncthreads();
        sm[threadIdx.x] += add;
        __syncthreads();
    }
    int base = sm[threadIdx.x] - s3;
    if (i4 < HT_INT4)
        data4[i4] = make_int4(base, base + s0, base + s1, base + s2);
    if (threadIdx.x == 255) bsum[blockIdx.x] = sm[255];
}

__global__ __launch_bounds__(1024) void scan2_kernel(
        const int* __restrict__ bsum, int* __restrict__ boff, int nblk) {
    __shared__ int sm[1024];
    int v = (threadIdx.x < nblk) ? bsum[threadIdx.x] : 0;
    sm[threadIdx.x] = v;
    __syncthreads();
    for (int off = 1; off < 1024; off <<= 1) {
        int add = (threadIdx.x >= off) ? sm[threadIdx.x - off] : 0;
        __syncthreads();
        sm[threadIdx.x] += add;
        __syncthreads();
    }
    if (threadIdx.x < nblk) boff[threadIdx.x] = sm[threadIdx.x] - v;
}

__global__ __launch_bounds__(256) void scan3_kernel(
        int4* data4, const int* __restrict__ boff) {
    int i4 = blockIdx.x * 256 + threadIdx.x;
    if (i4 < HT_INT4) {
        int b = boff[blockIdx.x];
        int4 v = data4[i4];
        v.x += b; v.y += b; v.z += b; v.w += b;
        data4[i4] = v;
    }
}

// ---- pass 1b: rank in LDS, write bucket-grouped payload runs ----
__global__ __launch_bounds__(256) void p1scat_kernel(
        const int* __restrict__ src, const int* __restrict__ dst,
        const int* __restrict__ etype, const int* __restrict__ offsT,
        unsigned* __restrict__ pay) {
    __shared__ int lhist[1024], lofs[1024], lcur[1024], goff[1024];
    __shared__ int partial[256];
    __shared__ unsigned stage[CH];
    __shared__ unsigned short sbkt[CH];
    int t = threadIdx.x;
    for (int i = t; i < 1024; i += 256) lhist[i] = 0;
    __syncthreads();
    int base = blockIdx.x * CH;
    int n = min(CH, Ee - base);
    for (int i = t; i < n; i += 256)
        atomicAdd(&lhist[dst[base + i] >> 6], 1);
    __syncthreads();
    // exclusive scan of 1024 bins
    int h0 = lhist[4*t], h1v = lhist[4*t+1], h2 = lhist[4*t+2], h3 = lhist[4*t+3];
    int s = h0 + h1v + h2 + h3;
    partial[t] = s;
    __syncthreads();
    for (int off = 1; off < 256; off <<= 1) {
        int add = (t >= off) ? partial[t - off] : 0;
        __syncthreads();
        partial[t] += add;
        __syncthreads();
    }
    int run = partial[t] - s;
    lofs[4*t] = run; lcur[4*t] = run; run += h0;
    lofs[4*t+1] = run; lcur[4*t+1] = run; run += h1v;
    lofs[4*t+2] = run; lcur[4*t+2] = run; run += h2;
    lofs[4*t+3] = run; lcur[4*t+3] = run;
    for (int k = t; k < NB; k += 256) goff[k] = offsT[k * COLS + blockIdx.x];
    __syncthreads();
    // split into stage (bucket-ordered)
    for (int i = t; i < n; i += 256) {
        int e = base + i;
        int dv = dst[e];
        int b = dv >> 6;
        int pos = atomicAdd(&lcur[b], 1);
        stage[pos] = ((unsigned)(dv & 63) << 20) | ((unsigned)etype[e] << 16)
                   | (unsigned)src[e];
        sbkt[pos] = (unsigned short)b;
    }
    __syncthreads();
    // output: consecutive j within a bucket -> consecutive global addresses
    for (int j = t; j < n; j += 256) {
        int b = sbkt[j];
        pay[goff[b] + (j - lofs[b])] = stage[j];
    }
}

// ---- pass 2: per-bucket counting sort, combo + csr32 (in place) ----
__global__ __launch_bounds__(256) void p2sort_kernel(
        const int* __restrict__ offsT, unsigned* pay,
        unsigned* __restrict__ combo) {
    __shared__ unsigned buf[CAP], outb[CAP];
    __shared__ int hist[1024], lofs[1024], lcur[1024], partial[256];
    int k = blockIdx.x, t = threadIdx.x;
    int base = offsT[k * COLS];
    int next = (k == NB - 1) ? Ee : offsT[(k + 1) * COLS];
    int n = next - base;
    for (int i = t; i < 1024; i += 256) hist[i] = 0;
    __syncthreads();
    for (int j = t; j < n; j += 256) {
        unsigned p = pay[base + j];
        buf[j] = p;
        atomicAdd(&hist[(p >> 16) & 0x3FFu], 1);
    }
    __syncthreads();
    int h0 = hist[4*t], h1v = hist[4*t+1], h2 = hist[4*t+2], h3 = hist[4*t+3];
    int s = h0 + h1v + h2 + h3;
    partial[t] = s;
    __syncthreads();
    for (int off = 1; off < 256; off <<= 1) {
        int add = (t >= off) ? partial[t - off] : 0;
        __syncthreads();
        partial[t] += add;
        __syncthreads();
    }
    int run = partial[t] - s;
    lofs[4*t] = run; lcur[4*t] = run; run += h0;
    lofs[4*t+1] = run; lcur[4*t+1] = run; run += h1v;
    lofs[4*t+2] = run; lcur[4*t+2] = run; run += h2;
    lofs[4*t+3] = run; lcur[4*t+3] = run;
    __syncthreads();
    // combo: seg = (k<<10)|bin = dst*16+r  (coalesced)
    for (int bin = t; bin < 1024; bin += 256) {
        int dglob = (k << 6) | (bin >> 4);
        if (dglob < Nn)
            combo[(k << 10) | bin] =
                ((unsigned)(base + lofs[bin]) << 8) | (unsigned)hist[bin];
    }
    if (k == NB - 1 && t == 0) combo[NSEG] = ((unsigned)Ee) << 8;
    // place sorted payload (r<<24)|(cnt<<16)|src
    for (int j = t; j < n; j += 256) {
        unsigned p = buf[j];
        int bin = (int)((p >> 16) & 0x3FFu);
        int pos = atomicAdd(&lcur[bin], 1);
        outb[pos] = (((p >> 16) & 15u) << 24) | ((unsigned)hist[bin] << 16)
                  | (p & 0xFFFFu);
    }
    __syncthreads();
    for (int j = t; j < n; j += 256) pay[base + j] = outb[j];   // csr32
}

// ---- layer 1: wave per dst; lane = slot(8) x chunk(8); h1 out bf16 ----
__global__ __launch_bounds__(256) void layer1_kernel(
        const unsigned* __restrict__ csr32, const unsigned* __restrict__ combo,
        const float* __restrict__ W1, const float* __restrict__ root1,
        const float* __restrict__ b1, unsigned short* __restrict__ h1b) {
    int d = (blockIdx.x * 256 + threadIdx.x) >> 6;
    int lane = threadIdx.x & 63;
    int slot = lane >> 3, chunk = lane & 7;
    if (d >= Nn) return;
    int beg = (int)(combo[d << 4] >> 8);
    int end = (int)(combo[(d + 1) << 4] >> 8);
    int deg = end - beg;
    float4 acc = make_float4(0.f, 0.f, 0.f, 0.f);
    const float* Wc = W1 + (chunk << 2);
    for (int i = 0; i < deg; i += 8) {
        int pos = i + slot;
        bool real = pos < deg;
        unsigned v = csr32[beg + (real ? pos : 0)];
        int s = real ? (int)(v & 0xffffu) : 0;
        int r = real ? (int)(v >> 24) : 0;
        float norm = real ? __builtin_amdgcn_rcpf((float)((v >> 16) & 255u)) : 0.f;
        float4 w = *(const float4*)(Wc + ((size_t)(r * Nn + s) << 5));
        acc.x = fmaf(norm, w.x, acc.x);
        acc.y = fmaf(norm, w.y, acc.y);
        acc.z = fmaf(norm, w.z, acc.z);
        acc.w = fmaf(norm, w.w, acc.w);
    }
#pragma unroll
    for (int m = 8; m <= 32; m <<= 1) {
        acc.x += __shfl_xor(acc.x, m, 64);
        acc.y += __shfl_xor(acc.y, m, 64);
        acc.z += __shfl_xor(acc.z, m, 64);
        acc.w += __shfl_xor(acc.w, m, 64);
    }
    if (slot == 0) {
        int hb = chunk << 2;
        float4 rt = *(const float4*)(root1 + (d << 5) + hb);
        float4 bb = *(const float4*)(b1 + hb);
        ushort4 ov;
        ov.x = f2bf(fmaxf(acc.x + rt.x + bb.x, 0.f));
        ov.y = f2bf(fmaxf(acc.y + rt.y + bb.y, 0.f));
        ov.z = f2bf(fmaxf(acc.z + rt.z + bb.z, 0.f));
        ov.w = f2bf(fmaxf(acc.w + rt.w + bb.w, 0.f));
        *(ushort4*)(h1b + (d << 5) + hb) = ov;   // lanes 0-7: one 64B line
    }
}

// ---- layer 2: wave per dst; per-edge W2 MAC from LDS; h1 in bf16 ----
__global__ __launch_bounds__(256) void layer2_kernel(
        const unsigned* __restrict__ csr32, const unsigned* __restrict__ combo,
        const unsigned short* __restrict__ h1b, const float* __restrict__ W2,
        const float* __restrict__ root2, const float* __restrict__ b2,
        float* __restrict__ out) {
    __shared__ float W2s[17 * 8 * W2C];   // [r][chunk][(h&3)*8 + l]
    for (int idx = threadIdx.x; idx < Rr * Hh * Ll; idx += 256) {
        int r = idx >> 8, h = (idx >> 3) & 31, l = idx & 7;
        W2s[((r << 3) | (h >> 2)) * W2C + ((h & 3) << 3) + l] = W2[idx];
    }
    for (int idx = threadIdx.x; idx < Hh * Ll; idx += 256) {
        int h = idx >> 3, l = idx & 7;
        W2s[(128 | (h >> 2)) * W2C + ((h & 3) << 3) + l] = root2[idx];
    }
    __syncthreads();

    int d = (blockIdx.x * 256 + threadIdx.x) >> 6;
    int lane = threadIdx.x & 63;
    int slot = lane >> 3, chunk = lane & 7;
    if (d >= Nn) return;
    int beg = (int)(combo[d << 4] >> 8);
    int end = (int)(combo[(d + 1) << 4] >> 8);
    int deg = end - beg;
    int degv = deg + 1;                 // + virtual root2 edge
    float acc[8] = {0.f, 0.f, 0.f, 0.f, 0.f, 0.f, 0.f, 0.f};
    const int hb = chunk << 2;
    for (int i = 0; i < degv; i += 8) {
        int pos = i + slot;
        bool real = pos < deg;
        bool virt = pos == deg;
        unsigned v = csr32[beg + (real ? pos : 0)];
        int s = virt ? d : (real ? (int)(v & 0xffffu) : 0);
        int r = virt ? 16 : (real ? (int)(v >> 24) : 0);
        float norm = virt ? 1.0f
                   : (real ? __builtin_amdgcn_rcpf((float)((v >> 16) & 255u)) : 0.f);
        ushort4 hu = *(const ushort4*)(h1b + (s << 5) + hb);
        float4 sa;
        sa.x = norm * bf2f(hu.x); sa.y = norm * bf2f(hu.y);
        sa.z = norm * bf2f(hu.z); sa.w = norm * bf2f(hu.w);
        const float* w = &W2s[((r << 3) | chunk) * W2C];
#pragma unroll
        for (int j2 = 0; j2 < 4; ++j2) {
            float saj = (j2 == 0) ? sa.x : (j2 == 1) ? sa.y : (j2 == 2) ? sa.z : sa.w;
            float4 w0 = *(const float4*)(w + j2 * 8);
            float4 w1 = *(const float4*)(w + j2 * 8 + 4);
            acc[0] = fmaf(saj, w0.x, acc[0]);
            acc[1] = fmaf(saj, w0.y, acc[1]);
            acc[2] = fmaf(saj, w0.z, acc[2]);
            acc[3] = fmaf(saj, w0.w, acc[3]);
            acc[4] = fmaf(saj, w1.x, acc[4]);
            acc[5] = fmaf(saj, w1.y, acc[5]);
            acc[6] = fmaf(saj, w1.z, acc[6]);
            acc[7] = fmaf(saj, w1.w, acc[7]);
        }
    }
#pragma unroll
    for (int m = 1; m <= 32; m <<= 1) {
#pragma unroll
        for (int l = 0; l < 8; ++l)
            acc[l] += __shfl_xor(acc[l], m, 64);
    }
    if (lane < 8) {
        float myv = acc[0];
#pragma unroll
        for (int l = 1; l < 8; ++l) myv = (lane == l) ? acc[l] : myv;
        float o = myv + b2[lane];
        out[(d << 3) | lane] = 1.0f / (1.0f + __expf(-o));
    }
}

extern "C" void kernel_launch(void* const* d_in, const int* in_sizes, int n_in,
                              void* d_out, int out_size, void* d_ws, size_t ws_size,
                              hipStream_t stream) {
    const int* edge_index = (const int*)d_in[0];   // (2, E) int32
    const int* etype      = (const int*)d_in[1];   // (E,)  int32
    const float* W1    = (const float*)d_in[2];    // (R,N,H) f32
    const float* root1 = (const float*)d_in[3];    // (N,H)
    const float* b1    = (const float*)d_in[4];    // (H,)
    const float* W2    = (const float*)d_in[5];    // (R,H,L)
    const float* root2 = (const float*)d_in[6];    // (H,L)
    const float* b2    = (const float*)d_in[7];    // (L,)
    float* out = (float*)d_out;                    // (N, L) f32

    const int* src = edge_index;       // row 0
    const int* dst = edge_index + Ee;  // row 1

    // workspace (int32 units):
    //   combo  [0,        800016)    p2sort writes; layers read (+sentinel)
    //   pay    [800016,   2400016)   p1scat -> p2sort (in-place -> csr32) -> layers
    //   h1b    [2400016,  3200016)   N*H bf16, layer1 -> layer2
    //   histT  [3200016,  3506560)   306544 = NB*COLS; scanned in place
    //   bsum   [3506560,  3506872)
    //   boff   [3506872,  3507184)
    // total 3,507,184 ints = 14.03 MB (<= 16.64 MB proven available)
    int* ws = (int*)d_ws;
    unsigned* combo        = (unsigned*)ws;
    unsigned* pay          = (unsigned*)(ws + 800016);
    unsigned short* h1b    = (unsigned short*)(ws + 2400016);
    int* histT             = ws + 3200016;
    int* bsum              = ws + 3506560;
    int* boff              = ws + 3506872;

    if (ws_size < (size_t)3507184 * sizeof(int)) return;  // diagnostic guard

    hipMemsetAsync(histT, 0, (size_t)(NB * COLS) * sizeof(int), stream);

    const int nblkSc = (HT_INT4 + 255) / 256;     // 300
    const int nblkL  = (Nn * 64 + 255) / 256;     // 12500 (wave per dst)

    p1hist_kernel<<<NBLK1, 256, 0, stream>>>(dst, histT);
    scan1_kernel<<<nblkSc, 256, 0, stream>>>((int4*)histT, bsum);
    scan2_kernel<<<1, 1024, 0, stream>>>(bsum, boff, nblkSc);
    scan3_kernel<<<nblkSc, 256, 0, stream>>>((int4*)histT, boff);
    p1scat_kernel<<<NBLK1, 256, 0, stream>>>(src, dst, etype, histT, pay);
    p2sort_kernel<<<NB, 256, 0, stream>>>(histT, pay, combo);
    layer1_kernel<<<nblkL, 256, 0, stream>>>(pay, combo, W1, root1, b1, h1b);
    layer2_kernel<<<nblkL, 256, 0, stream>>>(pay, combo, h1b, W2, root2, b2, out);
}

// Round 9
// 302.370 us; speedup vs baseline: 2.3110x; 1.0454x over previous
//
#include <hip/hip_runtime.h>
#include <hip/hip_bf16.h>

// RGCN: N=50000, R=16, H=32, L=8, E=1600000. Float tensors f32; h1 bf16.
// Build (unchanged from round 8, zero global atomics): two-level LDS bucket
// sort (p1hist -> scan -> p1scat -> p2sort) producing
// combo[seg]=(offs<<8)|cnt and csr32=(r<<24)|(k<<16)|src sorted by (dst,r).
// Layers (round 9): wave-per-dst, 16 EDGES IN FLIGHT per wave (two 8-slot
// halves issued back-to-back) -- round 8 had 8 lines in flight and ran at
// 1.7 TB/s (MLP-bound, FETCH already compulsory ~106MB).
#define Nn 50000
#define Rr 16
#define Hh 32
#define Ll 8
#define Ee 1600000
#define NSEG 800000
#define NB 782          // buckets = dst>>6
#define CH 4096         // edges per partition block
#define NBLK1 391       // ceil(E/CH)
#define COLS 392        // histT row stride
#define HT_INT4 76636   // NB*COLS/4
#define CAP 3072        // max edges per bucket
#define W2C 36

__device__ __forceinline__ float bf2f(unsigned short u) {
    return __uint_as_float(((unsigned)u) << 16);
}
__device__ __forceinline__ unsigned short f2bf(float f) {
    unsigned u = __float_as_uint(f);
    return (unsigned short)((u + 0x7FFFu + ((u >> 16) & 1u)) >> 16);  // RNE
}

// ---- pass 1a: per-block bucket histogram (LDS atomics only) ----
__global__ __launch_bounds__(256) void p1hist_kernel(
        const int* __restrict__ dst, int* __restrict__ histT) {
    __shared__ int hist[1024];
    for (int i = threadIdx.x; i < 1024; i += 256) hist[i] = 0;
    __syncthreads();
    int base = blockIdx.x * CH;
    int n = min(CH, Ee - base);
    for (int i = threadIdx.x; i < n; i += 256)
        atomicAdd(&hist[dst[base + i] >> 6], 1);
    __syncthreads();
    for (int k = threadIdx.x; k < NB; k += 256)
        histT[k * COLS + blockIdx.x] = hist[k];
}

// ---- exclusive scan over histT (in place), 4 elems/thread ----
__global__ __launch_bounds__(256) void scan1_kernel(
        int4* data4, int* __restrict__ bsum) {
    __shared__ int sm[256];
    int i4 = blockIdx.x * 256 + threadIdx.x;
    int4 v = make_int4(0, 0, 0, 0);
    if (i4 < HT_INT4) v = data4[i4];
    int s0 = v.x, s1 = s0 + v.y, s2 = s1 + v.z, s3 = s2 + v.w;
    sm[threadIdx.x] = s3;
    __syncthreads();
    for (int off = 1; off < 256; off <<= 1) {
        int add = (threadIdx.x >= off) ? sm[threadIdx.x - off] : 0;
        __syncthreads();
        sm[threadIdx.x] += add;
        __syncthreads();
    }
    int base = sm[threadIdx.x] - s3;
    if (i4 < HT_INT4)
        data4[i4] = make_int4(base, base + s0, base + s1, base + s2);
    if (threadIdx.x == 255) bsum[blockIdx.x] = sm[255];
}

__global__ __launch_bounds__(1024) void scan2_kernel(
        const int* __restrict__ bsum, int* __restrict__ boff, int nblk) {
    __shared__ int sm[1024];
    int v = (threadIdx.x < nblk) ? bsum[threadIdx.x] : 0;
    sm[threadIdx.x] = v;
    __syncthreads();
    for (int off = 1; off < 1024; off <<= 1) {
        int add = (threadIdx.x >= off) ? sm[threadIdx.x - off] : 0;
        __syncthreads();
        sm[threadIdx.x] += add;
        __syncthreads();
    }
    if (threadIdx.x < nblk) boff[threadIdx.x] = sm[threadIdx.x] - v;
}

__global__ __launch_bounds__(256) void scan3_kernel(
        int4* data4, const int* __restrict__ boff) {
    int i4 = blockIdx.x * 256 + threadIdx.x;
    if (i4 < HT_INT4) {
        int b = boff[blockIdx.x];
        int4 v = data4[i4];
        v.x += b; v.y += b; v.z += b; v.w += b;
        data4[i4] = v;
    }
}

// ---- pass 1b: rank in LDS, write bucket-grouped payload runs ----
__global__ __launch_bounds__(256) void p1scat_kernel(
        const int* __restrict__ src, const int* __restrict__ dst,
        const int* __restrict__ etype, const int* __restrict__ offsT,
        unsigned* __restrict__ pay) {
    __shared__ int lhist[1024], lofs[1024], lcur[1024], goff[1024];
    __shared__ int partial[256];
    __shared__ unsigned stage[CH];
    __shared__ unsigned short sbkt[CH];
    int t = threadIdx.x;
    for (int i = t; i < 1024; i += 256) lhist[i] = 0;
    __syncthreads();
    int base = blockIdx.x * CH;
    int n = min(CH, Ee - base);
    for (int i = t; i < n; i += 256)
        atomicAdd(&lhist[dst[base + i] >> 6], 1);
    __syncthreads();
    int h0 = lhist[4*t], h1v = lhist[4*t+1], h2 = lhist[4*t+2], h3 = lhist[4*t+3];
    int s = h0 + h1v + h2 + h3;
    partial[t] = s;
    __syncthreads();
    for (int off = 1; off < 256; off <<= 1) {
        int add = (t >= off) ? partial[t - off] : 0;
        __syncthreads();
        partial[t] += add;
        __syncthreads();
    }
    int run = partial[t] - s;
    lofs[4*t] = run; lcur[4*t] = run; run += h0;
    lofs[4*t+1] = run; lcur[4*t+1] = run; run += h1v;
    lofs[4*t+2] = run; lcur[4*t+2] = run; run += h2;
    lofs[4*t+3] = run; lcur[4*t+3] = run;
    for (int k = t; k < NB; k += 256) goff[k] = offsT[k * COLS + blockIdx.x];
    __syncthreads();
    for (int i = t; i < n; i += 256) {
        int e = base + i;
        int dv = dst[e];
        int b = dv >> 6;
        int pos = atomicAdd(&lcur[b], 1);
        stage[pos] = ((unsigned)(dv & 63) << 20) | ((unsigned)etype[e] << 16)
                   | (unsigned)src[e];
        sbkt[pos] = (unsigned short)b;
    }
    __syncthreads();
    for (int j = t; j < n; j += 256) {
        int b = sbkt[j];
        pay[goff[b] + (j - lofs[b])] = stage[j];
    }
}

// ---- pass 2: per-bucket counting sort, combo + csr32 (in place) ----
__global__ __launch_bounds__(256) void p2sort_kernel(
        const int* __restrict__ offsT, unsigned* pay,
        unsigned* __restrict__ combo) {
    __shared__ unsigned buf[CAP], outb[CAP];
    __shared__ int hist[1024], lofs[1024], lcur[1024], partial[256];
    int k = blockIdx.x, t = threadIdx.x;
    int base = offsT[k * COLS];
    int next = (k == NB - 1) ? Ee : offsT[(k + 1) * COLS];
    int n = next - base;
    for (int i = t; i < 1024; i += 256) hist[i] = 0;
    __syncthreads();
    for (int j = t; j < n; j += 256) {
        unsigned p = pay[base + j];
        buf[j] = p;
        atomicAdd(&hist[(p >> 16) & 0x3FFu], 1);
    }
    __syncthreads();
    int h0 = hist[4*t], h1v = hist[4*t+1], h2 = hist[4*t+2], h3 = hist[4*t+3];
    int s = h0 + h1v + h2 + h3;
    partial[t] = s;
    __syncthreads();
    for (int off = 1; off < 256; off <<= 1) {
        int add = (t >= off) ? partial[t - off] : 0;
        __syncthreads();
        partial[t] += add;
        __syncthreads();
    }
    int run = partial[t] - s;
    lofs[4*t] = run; lcur[4*t] = run; run += h0;
    lofs[4*t+1] = run; lcur[4*t+1] = run; run += h1v;
    lofs[4*t+2] = run; lcur[4*t+2] = run; run += h2;
    lofs[4*t+3] = run; lcur[4*t+3] = run;
    __syncthreads();
    for (int bin = t; bin < 1024; bin += 256) {
        int dglob = (k << 6) | (bin >> 4);
        if (dglob < Nn)
            combo[(k << 10) | bin] =
                ((unsigned)(base + lofs[bin]) << 8) | (unsigned)hist[bin];
    }
    if (k == NB - 1 && t == 0) combo[NSEG] = ((unsigned)Ee) << 8;
    for (int j = t; j < n; j += 256) {
        unsigned p = buf[j];
        int bin = (int)((p >> 16) & 0x3FFu);
        int pos = atomicAdd(&lcur[bin], 1);
        outb[pos] = (((p >> 16) & 15u) << 24) | ((unsigned)hist[bin] << 16)
                  | (p & 0xFFFFu);
    }
    __syncthreads();
    for (int j = t; j < n; j += 256) pay[base + j] = outb[j];   // csr32
}

// ---- layer 1: wave per dst; 16 edges in flight (two 8-slot halves) ----
__global__ __launch_bounds__(256) void layer1_kernel(
        const unsigned* __restrict__ csr32, const unsigned* __restrict__ combo,
        const float* __restrict__ W1, const float* __restrict__ root1,
        const float* __restrict__ b1, unsigned short* __restrict__ h1b) {
    int d = (blockIdx.x * 256 + threadIdx.x) >> 6;
    int lane = threadIdx.x & 63;
    int slot = lane >> 3, chunk = lane & 7;
    if (d >= Nn) return;
    int beg = (int)(combo[d << 4] >> 8);
    int end = (int)(combo[(d + 1) << 4] >> 8);
    int deg = end - beg;
    float4 acc = make_float4(0.f, 0.f, 0.f, 0.f);
    const float* Wc = W1 + (chunk << 2);
#pragma unroll 1
    for (int i = 0; i < deg; i += 16) {
        int p0 = i + slot, p1 = i + 8 + slot;
        bool r0 = p0 < deg, r1 = p1 < deg;
        unsigned v0 = csr32[beg + (r0 ? p0 : 0)];
        unsigned v1 = csr32[beg + (r1 ? p1 : 0)];
        float n0 = r0 ? __builtin_amdgcn_rcpf((float)((v0 >> 16) & 255u)) : 0.f;
        float n1 = r1 ? __builtin_amdgcn_rcpf((float)((v1 >> 16) & 255u)) : 0.f;
        const float4* a0 = (const float4*)(Wc +
            ((size_t)((int)(v0 >> 24) * Nn + (int)(v0 & 0xffffu)) << 5));
        const float4* a1 = (const float4*)(Wc +
            ((size_t)((int)(v1 >> 24) * Nn + (int)(v1 & 0xffffu)) << 5));
        float4 w0 = *a0;
        float4 w1 = *a1;
        acc.x = fmaf(n0, w0.x, acc.x); acc.y = fmaf(n0, w0.y, acc.y);
        acc.z = fmaf(n0, w0.z, acc.z); acc.w = fmaf(n0, w0.w, acc.w);
        acc.x = fmaf(n1, w1.x, acc.x); acc.y = fmaf(n1, w1.y, acc.y);
        acc.z = fmaf(n1, w1.z, acc.z); acc.w = fmaf(n1, w1.w, acc.w);
    }
#pragma unroll
    for (int m = 8; m <= 32; m <<= 1) {
        acc.x += __shfl_xor(acc.x, m, 64);
        acc.y += __shfl_xor(acc.y, m, 64);
        acc.z += __shfl_xor(acc.z, m, 64);
        acc.w += __shfl_xor(acc.w, m, 64);
    }
    if (slot == 0) {
        int hb = chunk << 2;
        float4 rt = *(const float4*)(root1 + (d << 5) + hb);
        float4 bb = *(const float4*)(b1 + hb);
        ushort4 ov;
        ov.x = f2bf(fmaxf(acc.x + rt.x + bb.x, 0.f));
        ov.y = f2bf(fmaxf(acc.y + rt.y + bb.y, 0.f));
        ov.z = f2bf(fmaxf(acc.z + rt.z + bb.z, 0.f));
        ov.w = f2bf(fmaxf(acc.w + rt.w + bb.w, 0.f));
        *(ushort4*)(h1b + (d << 5) + hb) = ov;
    }
}

// ---- layer 2: wave per dst; 16 edges in flight; per-edge W2 MAC (LDS) ----
__global__ __launch_bounds__(256) void layer2_kernel(
        const unsigned* __restrict__ csr32, const unsigned* __restrict__ combo,
        const unsigned short* __restrict__ h1b, const float* __restrict__ W2,
        const float* __restrict__ root2, const float* __restrict__ b2,
        float* __restrict__ out) {
    __shared__ float W2s[17 * 8 * W2C];   // [r][chunk][(h&3)*8 + l]
    for (int idx = threadIdx.x; idx < Rr * Hh * Ll; idx += 256) {
        int r = idx >> 8, h = (idx >> 3) & 31, l = idx & 7;
        W2s[((r << 3) | (h >> 2)) * W2C + ((h & 3) << 3) + l] = W2[idx];
    }
    for (int idx = threadIdx.x; idx < Hh * Ll; idx += 256) {
        int h = idx >> 3, l = idx & 7;
        W2s[(128 | (h >> 2)) * W2C + ((h & 3) << 3) + l] = root2[idx];
    }
    __syncthreads();

    int d = (blockIdx.x * 256 + threadIdx.x) >> 6;
    int lane = threadIdx.x & 63;
    int slot = lane >> 3, chunk = lane & 7;
    if (d >= Nn) return;
    int beg = (int)(combo[d << 4] >> 8);
    int end = (int)(combo[(d + 1) << 4] >> 8);
    int deg = end - beg;
    int degv = deg + 1;                 // + virtual root2 edge
    float acc[8] = {0.f, 0.f, 0.f, 0.f, 0.f, 0.f, 0.f, 0.f};
    const int hb = chunk << 2;
#pragma unroll 1
    for (int i = 0; i < degv; i += 16) {
        int p0 = i + slot, p1 = i + 8 + slot;
        bool re0 = p0 < deg, re1 = p1 < deg;
        bool vi0 = p0 == deg, vi1 = p1 == deg;
        unsigned v0 = csr32[beg + (re0 ? p0 : 0)];
        unsigned v1 = csr32[beg + (re1 ? p1 : 0)];
        int s0 = vi0 ? d : (re0 ? (int)(v0 & 0xffffu) : 0);
        int s1 = vi1 ? d : (re1 ? (int)(v1 & 0xffffu) : 0);
        int r0 = vi0 ? 16 : (re0 ? (int)(v0 >> 24) : 0);
        int r1 = vi1 ? 16 : (re1 ? (int)(v1 >> 24) : 0);
        float n0 = vi0 ? 1.0f
                 : (re0 ? __builtin_amdgcn_rcpf((float)((v0 >> 16) & 255u)) : 0.f);
        float n1 = vi1 ? 1.0f
                 : (re1 ? __builtin_amdgcn_rcpf((float)((v1 >> 16) & 255u)) : 0.f);
        ushort4 hu0 = *(const ushort4*)(h1b + (s0 << 5) + hb);
        ushort4 hu1 = *(const ushort4*)(h1b + (s1 << 5) + hb);
        float4 sa0, sa1;
        sa0.x = n0 * bf2f(hu0.x); sa0.y = n0 * bf2f(hu0.y);
        sa0.z = n0 * bf2f(hu0.z); sa0.w = n0 * bf2f(hu0.w);
        sa1.x = n1 * bf2f(hu1.x); sa1.y = n1 * bf2f(hu1.y);
        sa1.z = n1 * bf2f(hu1.z); sa1.w = n1 * bf2f(hu1.w);
        const float* w0p = &W2s[((r0 << 3) | chunk) * W2C];
        const float* w1p = &W2s[((r1 << 3) | chunk) * W2C];
#pragma unroll
        for (int j2 = 0; j2 < 4; ++j2) {
            float a0 = (j2 == 0) ? sa0.x : (j2 == 1) ? sa0.y : (j2 == 2) ? sa0.z : sa0.w;
            float4 wa = *(const float4*)(w0p + j2 * 8);
            float4 wb = *(const float4*)(w0p + j2 * 8 + 4);
            acc[0] = fmaf(a0, wa.x, acc[0]); acc[1] = fmaf(a0, wa.y, acc[1]);
            acc[2] = fmaf(a0, wa.z, acc[2]); acc[3] = fmaf(a0, wa.w, acc[3]);
            acc[4] = fmaf(a0, wb.x, acc[4]); acc[5] = fmaf(a0, wb.y, acc[5]);
            acc[6] = fmaf(a0, wb.z, acc[6]); acc[7] = fmaf(a0, wb.w, acc[7]);
        }
#pragma unroll
        for (int j2 = 0; j2 < 4; ++j2) {
            float a1 = (j2 == 0) ? sa1.x : (j2 == 1) ? sa1.y : (j2 == 2) ? sa1.z : sa1.w;
            float4 wa = *(const float4*)(w1p + j2 * 8);
            float4 wb = *(const float4*)(w1p + j2 * 8 + 4);
            acc[0] = fmaf(a1, wa.x, acc[0]); acc[1] = fmaf(a1, wa.y, acc[1]);
            acc[2] = fmaf(a1, wa.z, acc[2]); acc[3] = fmaf(a1, wa.w, acc[3]);
            acc[4] = fmaf(a1, wb.x, acc[4]); acc[5] = fmaf(a1, wb.y, acc[5]);
            acc[6] = fmaf(a1, wb.z, acc[6]); acc[7] = fmaf(a1, wb.w, acc[7]);
        }
    }
#pragma unroll
    for (int m = 1; m <= 32; m <<= 1) {
#pragma unroll
        for (int l = 0; l < 8; ++l)
            acc[l] += __shfl_xor(acc[l], m, 64);
    }
    if (lane < 8) {
        float myv = acc[0];
#pragma unroll
        for (int l = 1; l < 8; ++l) myv = (lane == l) ? acc[l] : myv;
        float o = myv + b2[lane];
        out[(d << 3) | lane] = 1.0f / (1.0f + __expf(-o));
    }
}

extern "C" void kernel_launch(void* const* d_in, const int* in_sizes, int n_in,
                              void* d_out, int out_size, void* d_ws, size_t ws_size,
                              hipStream_t stream) {
    const int* edge_index = (const int*)d_in[0];   // (2, E) int32
    const int* etype      = (const int*)d_in[1];   // (E,)  int32
    const float* W1    = (const float*)d_in[2];    // (R,N,H) f32
    const float* root1 = (const float*)d_in[3];    // (N,H)
    const float* b1    = (const float*)d_in[4];    // (H,)
    const float* W2    = (const float*)d_in[5];    // (R,H,L)
    const float* root2 = (const float*)d_in[6];    // (H,L)
    const float* b2    = (const float*)d_in[7];    // (L,)
    float* out = (float*)d_out;                    // (N, L) f32

    const int* src = edge_index;       // row 0
    const int* dst = edge_index + Ee;  // row 1

    // workspace (int32 units):
    //   combo  [0,        800016)    p2sort writes; layers read (+sentinel)
    //   pay    [800016,   2400016)   p1scat -> p2sort (in-place csr32) -> layers
    //   h1b    [2400016,  3200016)   N*H bf16, layer1 -> layer2
    //   histT  [3200016,  3506560)   NB*COLS; scanned in place
    //   bsum   [3506560,  3506872)
    //   boff   [3506872,  3507184)
    int* ws = (int*)d_ws;
    unsigned* combo        = (unsigned*)ws;
    unsigned* pay          = (unsigned*)(ws + 800016);
    unsigned short* h1b    = (unsigned short*)(ws + 2400016);
    int* histT             = ws + 3200016;
    int* bsum              = ws + 3506560;
    int* boff              = ws + 3506872;

    if (ws_size < (size_t)3507184 * sizeof(int)) return;  // diagnostic guard

    hipMemsetAsync(histT, 0, (size_t)(NB * COLS) * sizeof(int), stream);

    const int nblkSc = (HT_INT4 + 255) / 256;     // 300
    const int nblkL  = (Nn * 64 + 255) / 256;     // 12500 (wave per dst)

    p1hist_kernel<<<NBLK1, 256, 0, stream>>>(dst, histT);
    scan1_kernel<<<nblkSc, 256, 0, stream>>>((int4*)histT, bsum);
    scan2_kernel<<<1, 1024, 0, stream>>>(bsum, boff, nblkSc);
    scan3_kernel<<<nblkSc, 256, 0, stream>>>((int4*)histT, boff);
    p1scat_kernel<<<NBLK1, 256, 0, stream>>>(src, dst, etype, histT, pay);
    p2sort_kernel<<<NB, 256, 0, stream>>>(histT, pay, combo);
    layer1_kernel<<<nblkL, 256, 0, stream>>>(pay, combo, W1, root1, b1, h1b);
    layer2_kernel<<<nblkL, 256, 0, stream>>>(pay, combo, h1b, W2, root2, b2, out);
}